// Round 1
// baseline (109.635 us; speedup 1.0000x reference)
//
#include <hip/hip_runtime.h>

// B=16, R=360, D=64.  Single fused kernel — NO workspace use (avoids the
// 2 x 256 MiB workspace poison fills that dominated the timed window).
#define BATCH 16
#define RR    360
#define DD    64
#define TI    24               // i-rows per block -> 15 blocks/batch, 240 blocks total (~1/CU)
#define NBLK  (RR / TI)
#define CH    60               // x staging chunk rows
#define NCH   (RR / CH)
#define NT    384              // 6 waves

typedef _Float16 h2 __attribute__((ext_vector_type(2)));
typedef _Float16 h8 __attribute__((ext_vector_type(8)));

// out[b,i,j] = relu( sum_d relu(s[b,j,d] + t[b,i,d]) * Wcat[d] + bcat )
//   s[b,j,d] = sum_f x[b,j,f] * Wout[f][d]
//   t[b,i,d] = sum_f x[b,i,f] * Wout[64+f][d] + bout[d]
__global__ __launch_bounds__(NT) void fused_pairwise(
    const float* __restrict__ x, const float* __restrict__ Wout,
    const float* __restrict__ bout, const float* __restrict__ wcat,
    const float* __restrict__ bcat, float* __restrict__ out)
{
    // 46080 + 3072 + 15360 = 64512 B LDS
    __shared__ __align__(16) _Float16 s_tile[RR * DD];  // swizzled: 16B chunk k of row r at chunk k^(r&7)
    __shared__ __align__(16) _Float16 t_tile[TI * DD];  // unswizzled
    __shared__ __align__(16) float    xl[CH * DD];      // x staging (f32)

    const int tid = threadIdx.x;
    const int b   = blockIdx.y;
    const int i0  = blockIdx.x * TI;
    const int d   = tid & 63;
    const int sub = tid >> 6;                 // wave id 0..5

    // ---- stage W^T (f32, stride 68) into the s_tile area (transient overlay),
    //      and the i-tile's 24 x-rows into xl (exactly 384 float4)
    float* WTs = (float*)s_tile;              // [64][68]
    float* WTt = WTs + DD * 68;               // [64][68]  (2*64*68*4 = 34816 B <= 46080)
    for (int e = tid; e < 2 * DD * DD; e += NT) {
        const int f = e >> 6, dd = e & 63;
        const float v = Wout[e];
        if (f < DD) WTs[dd * 68 + f] = v;
        else        WTt[dd * 68 + (f - DD)] = v;
    }
    ((float4*)xl)[tid] = ((const float4*)(x + ((size_t)b * RR + i0) * DD))[tid];
    const float bv = bout[d];
    __syncthreads();

    // ---- hoist this thread's two W columns into registers (fully static indexing)
    float ws[DD], wt[DD];
    #pragma unroll
    for (int k = 0; k < DD / 4; ++k) {
        const float4 a = *(const float4*)&WTs[d * 68 + 4 * k];
        ws[4*k] = a.x; ws[4*k+1] = a.y; ws[4*k+2] = a.z; ws[4*k+3] = a.w;
        const float4 c = *(const float4*)&WTt[d * 68 + 4 * k];
        wt[4*k] = c.x; wt[4*k+1] = c.y; wt[4*k+2] = c.z; wt[4*k+3] = c.w;
    }

    // ---- t rows for this i-tile (4 rows per wave), f32 FMA, fp16 store
    #pragma unroll
    for (int qq = 0; qq < TI / 6; ++qq) {
        const int q = sub * (TI / 6) + qq;
        const float4* xr = (const float4*)&xl[q * DD];   // wave-uniform row -> LDS broadcast
        float a0 = bv, a1 = 0.f;
        #pragma unroll
        for (int k = 0; k < DD / 4; ++k) {
            const float4 xv = xr[k];
            a0 = fmaf(xv.x, wt[4*k  ], a0);
            a1 = fmaf(xv.y, wt[4*k+1], a1);
            a0 = fmaf(xv.z, wt[4*k+2], a0);
            a1 = fmaf(xv.w, wt[4*k+3], a1);
        }
        t_tile[q * DD + d] = (_Float16)(a0 + a1);
    }
    __syncthreads();   // WT overlay + xl free from here

    // ---- s rows for ALL 360 j, chunked x staging; swizzled fp16 store
    for (int c = 0; c < NCH; ++c) {
        const float4* xsrc = (const float4*)(x + ((size_t)b * RR + c * CH) * DD);
        for (int e = tid; e < CH * DD / 4; e += NT) ((float4*)xl)[e] = xsrc[e];
        __syncthreads();
        #pragma unroll 2
        for (int m = 0; m < CH / 6; ++m) {
            const int rl = sub + 6 * m;                  // wave-uniform
            const int r  = c * CH + rl;
            const float4* xr = (const float4*)&xl[rl * DD];
            float a0 = 0.f, a1 = 0.f;
            #pragma unroll
            for (int k = 0; k < DD / 4; ++k) {
                const float4 xv = xr[k];
                a0 = fmaf(xv.x, ws[4*k  ], a0);
                a1 = fmaf(xv.y, ws[4*k+1], a1);
                a0 = fmaf(xv.z, ws[4*k+2], a0);
                a1 = fmaf(xv.w, ws[4*k+3], a1);
            }
            // logical 16B chunk d>>3 stored at physical chunk (d>>3)^(r&7)
            const int pc = (d >> 3) ^ (r & 7);
            s_tile[r * DD + pc * 8 + (d & 7)] = (_Float16)(a0 + a1);
        }
        __syncthreads();
    }

    // ---- pairwise phase: lane j owns column j; loop 24 i-rows
    h2 wl[DD / 2];
    #pragma unroll
    for (int k = 0; k < DD / 2; ++k) {
        h2 w; w.x = (_Float16)wcat[2*k]; w.y = (_Float16)wcat[2*k+1];
        wl[k] = w;
    }
    const float bc = bcat[0];

    const int j = tid;
    if (j >= RR) return;                      // no barriers after this point

    // s row j: 8x ds_read_b128, XOR-deswizzled (8-way floor instead of 32-way conflict)
    h2 sr[DD / 2];
    #pragma unroll
    for (int k = 0; k < DD / 8; ++k) {
        const int pc = k ^ (j & 7);
        union { h8 v; h2 p[4]; } u;
        u.v = *(const h8*)&s_tile[j * DD + pc * 8];
        sr[4*k+0] = u.p[0]; sr[4*k+1] = u.p[1]; sr[4*k+2] = u.p[2]; sr[4*k+3] = u.p[3];
    }

    h2 zero; zero.x = (_Float16)0; zero.y = (_Float16)0;
    float* orow = out + ((size_t)b * RR * RR + (size_t)i0 * RR + j);

    #pragma unroll 4
    for (int ii = 0; ii < TI; ++ii) {
        const h2* trow = (const h2*)&t_tile[ii * DD];    // uniform -> LDS broadcast
        float a0 = bc, a1 = 0.f;
        #pragma unroll
        for (int k = 0; k < DD / 2; k += 2) {
            h2 p0 = sr[k]   + trow[k];                   // v_pk_add_f16
            h2 p1 = sr[k+1] + trow[k+1];
            p0 = __builtin_elementwise_max(p0, zero);    // v_pk_max_f16
            p1 = __builtin_elementwise_max(p1, zero);
#if __has_builtin(__builtin_amdgcn_fdot2)
            a0 = __builtin_amdgcn_fdot2(p0, wl[k],   a0, false);   // v_dot2_f32_f16
            a1 = __builtin_amdgcn_fdot2(p1, wl[k+1], a1, false);
#else
            a0 = fmaf((float)p0.x, (float)wl[k].x,   a0);
            a0 = fmaf((float)p0.y, (float)wl[k].y,   a0);
            a1 = fmaf((float)p1.x, (float)wl[k+1].x, a1);
            a1 = fmaf((float)p1.y, (float)wl[k+1].y, a1);
#endif
        }
        const float acc = a0 + a1;
        orow[(size_t)ii * RR] = acc > 0.f ? acc : 0.f;   // coalesced across lanes
    }
}

extern "C" void kernel_launch(void* const* d_in, const int* in_sizes, int n_in,
                              void* d_out, int out_size, void* d_ws, size_t ws_size,
                              hipStream_t stream) {
    (void)d_ws; (void)ws_size;                // deliberately unused: no workspace -> no poison fills
    const float* x    = (const float*)d_in[0];   // (16, 360, 64)
    const float* Wout = (const float*)d_in[1];   // (128, 64)
    const float* bout = (const float*)d_in[2];   // (64,)
    const float* Wcat = (const float*)d_in[3];   // (64, 1)
    const float* bcat = (const float*)d_in[4];   // (1,)
    float* out = (float*)d_out;                  // (16, 360, 360, 1) fp32

    fused_pairwise<<<dim3(NBLK, BATCH), dim3(NT), 0, stream>>>(
        x, Wout, bout, Wcat, bcat, out);
}

// Round 2
// 108.661 us; speedup vs baseline: 1.0090x; 1.0090x over previous
//
#include <hip/hip_runtime.h>

// B=16, R=360, D=64.  Single fused kernel, 2-D tiled (60x60 output tiles).
// No workspace use (workspace poison fills dominated the original 79 us).
#define BATCH 16
#define RR    360
#define DD    64
#define TT    60               // tile edge (both i and j)
#define NTB   (RR / TT)        // 6 -> grid 6 x 6 x 16 = 576 blocks
#define NT    384              // 6 waves

typedef _Float16 h2 __attribute__((ext_vector_type(2)));
typedef _Float16 h8 __attribute__((ext_vector_type(8)));

// out[b,i,j] = relu( sum_d relu(s[b,j,d] + t[b,i,d]) * Wcat[d] + bcat )
//   s[b,j,d] = sum_f x[b,j,f] * Wout[f][d]
//   t[b,i,d] = sum_f x[b,i,f] * Wout[64+f][d] + bout[d]
// Waves 0-2 compute t-rows (hold only W[64+f][d] in regs);
// waves 3-5 compute s-rows (hold only W[f][d]).  4 FMA chains per row.
__global__ __launch_bounds__(NT) void fused_tile(
    const float* __restrict__ x, const float* __restrict__ Wout,
    const float* __restrict__ bout, const float* __restrict__ wcat,
    const float* __restrict__ bcat, float* __restrict__ out)
{
    __shared__ __align__(16) float    xl[2 * TT * DD];   // 60 i-rows then 60 j-rows (30720 B)
    __shared__ __align__(16) _Float16 t_tile[TT * DD];   // 7680 B, unswizzled
    __shared__ __align__(16) _Float16 s_tile[TT * DD];   // 7680 B, chunk-swizzled

    const int tid = threadIdx.x;
    const int jt  = blockIdx.x;
    const int it  = blockIdx.y;
    const int b   = blockIdx.z;
    const int i0  = it * TT, j0 = jt * TT;
    const int d   = tid & 63;
    const int sub = tid >> 6;                 // wave id 0..5

    // ---- stage x rows for both tiles (1920 float4 total)
    {
        const float4* xi = (const float4*)(x + ((size_t)b * RR + i0) * DD);
        const float4* xj = (const float4*)(x + ((size_t)b * RR + j0) * DD);
        for (int e = tid; e < TT * DD / 4; e += NT) {
            ((float4*)xl)[e] = xi[e];
            ((float4*)xl)[TT * DD / 4 + e] = xj[e];
        }
    }

    // ---- this thread's W column (64 regs): coalesced 256B row reads, L1-resident
    const bool is_t = sub < 3;
    float wc[DD];
    {
        const float* wbase = Wout + (is_t ? DD * DD : 0) + d;
        #pragma unroll
        for (int f = 0; f < DD; ++f) wc[f] = wbase[(size_t)f * DD];
    }
    const float bv = is_t ? bout[d] : 0.f;
    __syncthreads();

    // ---- row compute: 20 rows per wave, 4 independent FMA chains per row
    {
        const int    w   = is_t ? sub : sub - 3;
        const float* xr0 = is_t ? xl : xl + TT * DD;
        #pragma unroll 2
        for (int m = 0; m < TT / 3; ++m) {
            const int r = w * (TT / 3) + m;
            const float4* xr = (const float4*)&xr0[r * DD];   // wave-uniform -> LDS broadcast
            float a0 = bv, a1 = 0.f, a2 = 0.f, a3 = 0.f;
            #pragma unroll
            for (int k = 0; k < DD / 4; ++k) {
                const float4 xv = xr[k];
                a0 = fmaf(xv.x, wc[4*k  ], a0);
                a1 = fmaf(xv.y, wc[4*k+1], a1);
                a2 = fmaf(xv.z, wc[4*k+2], a2);
                a3 = fmaf(xv.w, wc[4*k+3], a3);
            }
            const _Float16 v = (_Float16)((a0 + a1) + (a2 + a3));
            if (is_t) {
                t_tile[r * DD + d] = v;
            } else {
                // logical 16B chunk d>>3 stored at physical chunk (d>>3)^(r&7)
                const int pc = (d >> 3) ^ (r & 7);
                s_tile[r * DD + pc * 8 + (d & 7)] = v;
            }
        }
    }
    __syncthreads();

    // ---- pairwise: lane j owns column j (lanes 60..63 masked), 10 i-rows per wave
    h2 wl[DD / 2];
    #pragma unroll
    for (int k = 0; k < DD / 2; ++k) {
        h2 w; w.x = (_Float16)wcat[2*k]; w.y = (_Float16)wcat[2*k+1];
        wl[k] = w;
    }
    const float bc = bcat[0];

    const int j  = d;
    const int jj = j < TT ? j : TT - 1;       // clamp for safe LDS reads
    h2 sr[DD / 2];
    #pragma unroll
    for (int k = 0; k < DD / 8; ++k) {
        const int pc = k ^ (jj & 7);          // XOR-deswizzle (8-way floor vs 32-way)
        union { h8 v; h2 p[4]; } u;
        u.v = *(const h8*)&s_tile[jj * DD + pc * 8];
        sr[4*k+0] = u.p[0]; sr[4*k+1] = u.p[1]; sr[4*k+2] = u.p[2]; sr[4*k+3] = u.p[3];
    }

    h2 zero; zero.x = (_Float16)0; zero.y = (_Float16)0;
    const bool jvalid = j < TT;
    float* ob = out + (size_t)b * RR * RR + (size_t)i0 * RR + j0 + j;

    #pragma unroll 2
    for (int ii = 0; ii < TT / 6; ++ii) {
        const int i = sub * (TT / 6) + ii;                // wave-uniform, 0..59
        const h2* trow = (const h2*)&t_tile[i * DD];      // uniform -> LDS broadcast
        float a0 = bc, a1 = 0.f;
        #pragma unroll
        for (int k = 0; k < DD / 2; k += 2) {
            h2 p0 = sr[k]   + trow[k];                    // v_pk_add_f16
            h2 p1 = sr[k+1] + trow[k+1];
            p0 = __builtin_elementwise_max(p0, zero);     // v_pk_max_f16
            p1 = __builtin_elementwise_max(p1, zero);
#if __has_builtin(__builtin_amdgcn_fdot2)
            a0 = __builtin_amdgcn_fdot2(p0, wl[k],   a0, false);   // v_dot2_f32_f16
            a1 = __builtin_amdgcn_fdot2(p1, wl[k+1], a1, false);
#else
            a0 = fmaf((float)p0.x, (float)wl[k].x,   a0);
            a0 = fmaf((float)p0.y, (float)wl[k].y,   a0);
            a1 = fmaf((float)p1.x, (float)wl[k+1].x, a1);
            a1 = fmaf((float)p1.y, (float)wl[k+1].y, a1);
#endif
        }
        const float acc = a0 + a1;
        if (jvalid) ob[(size_t)i * RR] = acc > 0.f ? acc : 0.f;   // coalesced across lanes
    }
}

extern "C" void kernel_launch(void* const* d_in, const int* in_sizes, int n_in,
                              void* d_out, int out_size, void* d_ws, size_t ws_size,
                              hipStream_t stream) {
    (void)d_ws; (void)ws_size;               // deliberately unused: no workspace poison
    const float* x    = (const float*)d_in[0];   // (16, 360, 64)
    const float* Wout = (const float*)d_in[1];   // (128, 64)
    const float* bout = (const float*)d_in[2];   // (64,)
    const float* Wcat = (const float*)d_in[3];   // (64, 1)
    const float* bcat = (const float*)d_in[4];   // (1,)
    float* out = (float*)d_out;                  // (16, 360, 360, 1) fp32

    fused_tile<<<dim3(NTB, NTB, BATCH), dim3(NT), 0, stream>>>(
        x, Wout, bout, Wcat, bcat, out);
}

// Round 3
// 81.857 us; speedup vs baseline: 1.3393x; 1.3275x over previous
//
#include <hip/hip_runtime.h>

// B=16, R=360, D=64.
// Two kernels, ZERO LDS (rounds 1-2 were LDS-issue-bound: ~7K wave-uniform
// ds_read per CU serialized on the single LDS pipe -> 53 us regardless of
// tiling).  All wave-uniform operands (x rows, t rows, W_cat) are read from
// global with scalar-uniform addresses (s_load / K$, separate pipe); per-lane
// operands (W columns, s rows) are coalesced VMEM.
// Workspace deliberately unused (256 MiB poison fills dominated round 0);
// inter-kernel scratch is static __device__ memory (same cross-kernel
// visibility semantics as the proven d_ws version).
#define BATCH 16
#define RR    360
#define DD    64
#define RPB   16   // rows per block in precompute kernel (4 waves x 4 rows)
#define TI    8    // i-rows per block in pairwise kernel

typedef _Float16 h2 __attribute__((ext_vector_type(2)));

__device__ _Float16 g_s[BATCH * RR * DD];   // s[b,r,d] fp16
__device__ _Float16 g_t[BATCH * RR * DD];   // t[b,r,d] fp16
__device__ _Float16 g_w[DD];                // W_cat fp16

// Kernel A: s[b,r,d] = sum_f x[b,r,f] * W_out[f][d]
//           t[b,r,d] = sum_f x[b,r,f] * W_out[64+f][d] + b_out[d]
// No LDS: W columns -> 128 VGPRs via coalesced loads (L2-resident, 32 KB);
// x rows are wave-uniform -> s_load through the K$ (readfirstlane makes the
// wave id provably uniform to the compiler).
__global__ __launch_bounds__(256) void precompute_st(
    const float* __restrict__ x, const float* __restrict__ Wout,
    const float* __restrict__ bout, const float* __restrict__ wcat)
{
    const int tid  = threadIdx.x;
    const int d    = tid & 63;
    const int subu = __builtin_amdgcn_readfirstlane(tid >> 6);  // wave id 0..3, uniform
    const int row0 = blockIdx.x * RPB;

    if (blockIdx.x == 0 && tid < DD) g_w[tid] = (_Float16)wcat[tid];

    // this thread's two W columns (coalesced 256B per f across the wave)
    float ws[DD], wt[DD];
    #pragma unroll
    for (int f = 0; f < DD; ++f) {
        ws[f] = Wout[f * DD + d];
        wt[f] = Wout[(DD + f) * DD + d];
    }
    const float bv = bout[d];

    #pragma unroll
    for (int q = 0; q < RPB / 4; ++q) {
        const int r = row0 + subu * (RPB / 4) + q;          // wave-uniform row
        const float* xr = x + (size_t)r * DD;               // uniform addr -> s_load
        float s0 = 0.f, s1 = 0.f, t0 = bv, t1 = 0.f;        // 4 independent chains
        #pragma unroll
        for (int k = 0; k < DD; k += 2) {
            const float x0 = xr[k], x1 = xr[k + 1];
            s0 = fmaf(x0, ws[k],     s0);
            s1 = fmaf(x1, ws[k + 1], s1);
            t0 = fmaf(x0, wt[k],     t0);
            t1 = fmaf(x1, wt[k + 1], t1);
        }
        g_s[(size_t)r * DD + d] = (_Float16)(s0 + s1);
        g_t[(size_t)r * DD + d] = (_Float16)(t0 + t1);
    }
}

// Kernel B: out[b,i,j] = relu( sum_d relu(s[b,j,d] + t[b,i,d]) * Wcat[d] + bcat )
// No LDS.  Lane j holds s-row j in 32 VGPRs (coalesced VMEM); t-row address is
// fully uniform (blockIdx + loop var only) -> s_load/K$; W_cat uniform -> s_load.
// Inner op: v_pk_add_f16 + v_pk_max_f16 + v_dot2_f32_f16, dual accumulators.
__global__ __launch_bounds__(384) void pairwise_out(
    const float* __restrict__ bcat, float* __restrict__ out)
{
    const int tid = threadIdx.x;
    const int b   = blockIdx.y;
    const int i0  = blockIdx.x * TI;
    const float bc = bcat[0];

    const h2* s_h = (const h2*)g_s;
    const h2* t_h = (const h2*)g_t;
    const h2* w_h = (const h2*)g_w;

    h2 wl[DD / 2];
    #pragma unroll
    for (int k = 0; k < DD / 2; ++k) wl[k] = w_h[k];        // uniform -> s_load

    const int j = tid;
    if (j >= RR) return;                                    // no barriers in kernel

    h2 sr[DD / 2];
    const h2* srow = s_h + ((size_t)b * RR + j) * (DD / 2);
    #pragma unroll
    for (int k = 0; k < DD / 2; ++k) sr[k] = srow[k];       // 8x b128, coalesced

    h2 zero; zero.x = (_Float16)0; zero.y = (_Float16)0;

    float* orow = out + ((size_t)b * RR * RR + (size_t)i0 * RR + j);
    const h2* tbase = t_h + ((size_t)b * RR + i0) * (DD / 2);

    #pragma unroll
    for (int ii = 0; ii < TI; ++ii) {
        const h2* trow = tbase + ii * (DD / 2);             // fully uniform -> s_load
        float a0 = bc, a1 = 0.f;
        #pragma unroll
        for (int k = 0; k < DD / 2; k += 2) {
            h2 p0 = sr[k]   + trow[k];                      // v_pk_add_f16
            h2 p1 = sr[k+1] + trow[k+1];
            p0 = __builtin_elementwise_max(p0, zero);       // v_pk_max_f16
            p1 = __builtin_elementwise_max(p1, zero);
#if __has_builtin(__builtin_amdgcn_fdot2)
            a0 = __builtin_amdgcn_fdot2(p0, wl[k],   a0, false);  // v_dot2_f32_f16
            a1 = __builtin_amdgcn_fdot2(p1, wl[k+1], a1, false);
#else
            a0 = fmaf((float)p0.x, (float)wl[k].x,   a0);
            a0 = fmaf((float)p0.y, (float)wl[k].y,   a0);
            a1 = fmaf((float)p1.x, (float)wl[k+1].x, a1);
            a1 = fmaf((float)p1.y, (float)wl[k+1].y, a1);
#endif
        }
        const float acc = a0 + a1;
        orow[(size_t)ii * RR] = acc > 0.f ? acc : 0.f;      // coalesced across lanes
    }
}

extern "C" void kernel_launch(void* const* d_in, const int* in_sizes, int n_in,
                              void* d_out, int out_size, void* d_ws, size_t ws_size,
                              hipStream_t stream) {
    (void)d_ws; (void)ws_size;    // deliberately unused: no workspace -> no poison fills
    const float* x    = (const float*)d_in[0];   // (16, 360, 64)
    const float* Wout = (const float*)d_in[1];   // (128, 64)
    const float* bout = (const float*)d_in[2];   // (64,)
    const float* Wcat = (const float*)d_in[3];   // (64, 1)
    const float* bcat = (const float*)d_in[4];   // (1,)
    float* out = (float*)d_out;                  // (16, 360, 360, 1) fp32

    precompute_st<<<dim3(BATCH * RR / RPB), dim3(256), 0, stream>>>(
        x, Wout, bout, Wcat);
    pairwise_out<<<dim3(RR / TI, BATCH), dim3(384), 0, stream>>>(
        bcat, out);
}